// Round 15
// baseline (732.838 us; speedup 1.0000x reference)
//
#include <hip/hip_runtime.h>

#define HID 52
#define HID2 104
#define P1_CHUNK 8192
#define NBIN_MAX 512      // bins of 256 nodes; N <= 131072
#define HSTRIDE 136
#define BINCAP 10240      // fixed bin capacity (mean 8192, sigma ~90 -> 22-sigma margin)
#define SR_STRIDE 14336   // srcsorted per-bin stride (BINCAP + 256*15 pad, rounded)

typedef unsigned short ushort_t;
typedef unsigned int uint_t;
typedef short bf16x8 __attribute__((ext_vector_type(8)));
typedef float f32x4 __attribute__((ext_vector_type(4)));
typedef float f32x2 __attribute__((ext_vector_type(2)));

__device__ __forceinline__ ushort_t f2bf(float f) {
    union { float f; uint_t u; } c; c.f = f;
    uint_t u = c.u + 0x7FFFu + ((c.u >> 16) & 1u);   // RNE
    return (ushort_t)(u >> 16);
}
__device__ __forceinline__ float bflo(uint_t u) {
    union { uint_t u; float f; } c; c.u = u << 16; return c.f;
}
__device__ __forceinline__ float bfhi(uint_t u) {
    union { uint_t u; float f; } c; c.u = u & 0xFFFF0000u; return c.f;
}
// raw pair: (a,b) reinterpreted as two f32 -> the two ODD (hi) channels, noisy-mantissa
__device__ __forceinline__ f32x2 rawpair(uint_t a, uint_t b) {
    union { uint_t u; float f; } ca, cb; ca.u = a; cb.u = b;
    return (f32x2){ca.f, cb.f};
}
// shifted pair: (a<<16, b<<16) -> the two EVEN (lo) channels, exact
__device__ __forceinline__ f32x2 shlpair(uint_t a, uint_t b) {
    union { uint_t u; float f; } ca, cb; ca.u = a << 16; cb.u = b << 16;
    return (f32x2){ca.f, cb.f};
}
// in-place packed add: a += b in ONE VOP3P instr ("+v" ties dst=src0)
__device__ __forceinline__ void pkacc(f32x2& a, f32x2 b) {
    asm("v_pk_add_f32 %0, %0, %1" : "+v"(a) : "v"(b));
}
// cross-lane xor within 32-lane halves via ds_swizzle BitMode (imm = (xor<<10)|0x1F)
template<int IMM>
__device__ __forceinline__ f32x2 swz2(f32x2 v) {
    union { float f; int i; } a, b; a.f = v.x; b.f = v.y;
    int ra = __builtin_amdgcn_ds_swizzle(a.i, IMM);
    int rb = __builtin_amdgcn_ds_swizzle(b.i, IMM);
    union { int i; float f; } c, d; c.i = ra; d.i = rb;
    return (f32x2){c.f, d.f};
}
// xor-32 across 64-lane wave (ds_swizzle BitMode caps at 32 lanes)
__device__ __forceinline__ f32x2 sh32(f32x2 v) {
    f32x2 r;
    r.x = __shfl_xor(v.x, 32);
    r.y = __shfl_xor(v.y, 32);
    return r;
}

// ---------- pass 1: bin-partition, LDS staging, fixed bins; 512 threads ----------
__global__ __launch_bounds__(512) void pass1_kernel(const int* __restrict__ src,
                                                    const int* __restrict__ dst,
                                                    int* __restrict__ gcnt,
                                                    uint_t* __restrict__ packed, int E) {
    __shared__ uint_t stage[P1_CHUNK];
    __shared__ ushort_t sbin[P1_CHUNK];
    __shared__ int cnt[NBIN_MAX];
    __shared__ int curs[NBIN_MAX];
    __shared__ int diff[NBIN_MAX];
    __shared__ int wsum[8];
    int tid = threadIdx.x;               // 0..511
    int lane = tid & 63, wv = tid >> 6;  // 8 waves
    cnt[tid] = 0;
    __syncthreads();
    int base = blockIdx.x * P1_CHUNK;
    int cend = min(P1_CHUNK, E - base);
    int nq = cend >> 2;
    const uint4* d4p = (const uint4*)(dst + base);   // base % 4 == 0 -> 16B aligned
    const uint4* s4p = (const uint4*)(src + base);
    for (int j = tid; j < nq; j += 512) {
        uint4 d = d4p[j];
        atomicAdd(&cnt[d.x >> 8], 1);
        atomicAdd(&cnt[d.y >> 8], 1);
        atomicAdd(&cnt[d.z >> 8], 1);
        atomicAdd(&cnt[d.w >> 8], 1);
    }
    for (int i = (nq << 2) + tid; i < cend; i += 512)
        atomicAdd(&cnt[((uint_t)dst[base + i]) >> 8], 1);
    __syncthreads();
    int c = cnt[tid];
    int inc = c;
#pragma unroll
    for (int off = 1; off < 64; off <<= 1) {
        int t = __shfl_up(inc, off);
        if (lane >= off) inc += t;
    }
    if (lane == 63) wsum[wv] = inc;
    __syncthreads();
    int wpre = 0;
#pragma unroll
    for (int i = 0; i < 7; i++) wpre += (i < wv) ? wsum[i] : 0;
    int ex = wpre + inc - c;
    curs[tid] = ex;
    int g = c ? (tid * BINCAP + atomicAdd(&gcnt[tid], c)) : 0;
    diff[tid] = g - ex;
    __syncthreads();
    for (int j = tid; j < nq; j += 512) {
        uint4 d = d4p[j];
        uint4 s = s4p[j];
        int b, pos;
        b = d.x >> 8; pos = atomicAdd(&curs[b], 1);
        stage[pos] = (s.x << 8) | (d.x & 255u); sbin[pos] = (ushort_t)b;
        b = d.y >> 8; pos = atomicAdd(&curs[b], 1);
        stage[pos] = (s.y << 8) | (d.y & 255u); sbin[pos] = (ushort_t)b;
        b = d.z >> 8; pos = atomicAdd(&curs[b], 1);
        stage[pos] = (s.z << 8) | (d.z & 255u); sbin[pos] = (ushort_t)b;
        b = d.w >> 8; pos = atomicAdd(&curs[b], 1);
        stage[pos] = (s.w << 8) | (d.w & 255u); sbin[pos] = (ushort_t)b;
    }
    for (int i = (nq << 2) + tid; i < cend; i += 512) {
        uint_t d = (uint_t)dst[base + i];
        uint_t s = (uint_t)src[base + i];
        int b = d >> 8;
        int pos = atomicAdd(&curs[b], 1);
        stage[pos] = (s << 8) | (d & 255u);
        sbin[pos] = (ushort_t)b;
    }
    __syncthreads();
    for (int i = tid; i < cend; i += 512) {
        packed[diff[sbin[i]] + i] = stage[i];
    }
}

// ---------- mid: pass2 + conv_x(8ch) + pad rows + weight conversion, one dispatch ----------
__global__ __launch_bounds__(256) void mid_kernel(const uint_t* __restrict__ packed,
                                                  const int* __restrict__ gcnt,
                                                  int* __restrict__ srcsorted,
                                                  int* __restrict__ nrs,
                                                  int* __restrict__ ndeg,
                                                  const float* __restrict__ x,
                                                  const float* __restrict__ w1,
                                                  const float* __restrict__ w2,
                                                  const float* __restrict__ lin_w,
                                                  ushort_t* __restrict__ xb,
                                                  ushort_t* __restrict__ h1b,
                                                  ushort_t* __restrict__ h2b,
                                                  ushort_t* __restrict__ w1f,
                                                  ushort_t* __restrict__ w2f,
                                                  ushort_t* __restrict__ linf,
                                                  int N, int nbin, int nconv) {
    __shared__ int hist[256];
    __shared__ int curs[256];
    __shared__ int wsum[4];
    int blk = blockIdx.x;
    int tid = threadIdx.x;
    if (blk < nbin) {
        int b = blk;
        int lane = tid & 63, wv = tid >> 6;
        hist[tid] = 0;
        __syncthreads();
        int beg = b * BINCAP;                      // multiple of 4 -> 16B aligned
        int cntE = gcnt[b];
        int nq = cntE >> 2;
        const uint4* p4p = (const uint4*)(packed + beg);
        for (int j = tid; j < nq; j += 256) {
            uint4 p = p4p[j];
            atomicAdd(&hist[p.x & 255u], 1);
            atomicAdd(&hist[p.y & 255u], 1);
            atomicAdd(&hist[p.z & 255u], 1);
            atomicAdd(&hist[p.w & 255u], 1);
        }
        for (int i = (nq << 2) + tid; i < cntE; i += 256)
            atomicAdd(&hist[packed[beg + i] & 255u], 1);
        __syncthreads();
        int v = hist[tid];
        int pv = (v + 15) & ~15;
        int inc = pv;
#pragma unroll
        for (int off = 1; off < 64; off <<= 1) {
            int t = __shfl_up(inc, off);
            if (lane >= off) inc += t;
        }
        if (lane == 63) wsum[wv] = inc;
        __syncthreads();
        int wpre = 0;
#pragma unroll
        for (int i = 0; i < 3; i++) wpre += (i < wv) ? wsum[i] : 0;
        int start = b * SR_STRIDE + wpre + inc - pv;
        int node = b * 256 + tid;
        if (node < N) { nrs[node] = start; ndeg[node] = pv; }
        curs[tid] = start;
        __syncthreads();
        for (int j = tid; j < nq; j += 256) {
            uint4 p = p4p[j];
            int pos;
            pos = atomicAdd(&curs[p.x & 255u], 1); srcsorted[pos] = (int)(p.x >> 8);
            pos = atomicAdd(&curs[p.y & 255u], 1); srcsorted[pos] = (int)(p.y >> 8);
            pos = atomicAdd(&curs[p.z & 255u], 1); srcsorted[pos] = (int)(p.z >> 8);
            pos = atomicAdd(&curs[p.w & 255u], 1); srcsorted[pos] = (int)(p.w >> 8);
        }
        for (int i = (nq << 2) + tid; i < cntE; i += 256) {
            uint_t p = packed[beg + i];
            int pos = atomicAdd(&curs[p & 255u], 1);
            srcsorted[pos] = (int)(p >> 8);
        }
        __syncthreads();
        for (int i = start + v; i < start + pv; i++) srcsorted[i] = N;   // zero-row pads
        return;
    }
    if (blk < nbin + nconv) {
        int t = (blk - nbin) * 256 + tid;
        if (t >= N * 8) return;
        int node = t >> 3, pp = t & 7, c0 = pp * 8;
        uint4 u = make_uint4(0, 0, 0, 0);
        if (c0 < 48) {
            float4 xa = *(const float4*)(x + (size_t)node * HID + c0);
            float4 xc = *(const float4*)(x + (size_t)node * HID + c0 + 4);
            u.x = (uint_t)f2bf(xa.x) | ((uint_t)f2bf(xa.y) << 16);
            u.y = (uint_t)f2bf(xa.z) | ((uint_t)f2bf(xa.w) << 16);
            u.z = (uint_t)f2bf(xc.x) | ((uint_t)f2bf(xc.y) << 16);
            u.w = (uint_t)f2bf(xc.z) | ((uint_t)f2bf(xc.w) << 16);
        } else if (c0 == 48) {
            float4 xa = *(const float4*)(x + (size_t)node * HID + 48);
            u.x = (uint_t)f2bf(xa.x) | ((uint_t)f2bf(xa.y) << 16);
            u.y = (uint_t)f2bf(xa.z) | ((uint_t)f2bf(xa.w) << 16);
        }
        *(uint4*)(xb + (size_t)node * 64 + c0) = u;
        return;
    }
    if (blk == nbin + nconv) {
        ushort_t* arr = (tid < 64) ? xb : (tid < 128) ? h1b : h2b;  // 192-255 dup h2b: benign
        arr[(size_t)N * 64 + (tid & 63)] = 0;
        return;
    }
    int gid = (blk - nbin - nconv - 1) * 4 + (tid >> 6);
    int lane = tid & 63;
    if (gid >= 122) return;
    int m = lane & 15, q = lane >> 4;
    ushort_t o[8];
    ushort_t* dstp;
    if (gid < 42) {
        int l = gid / 14, r = gid % 14, ct = r >> 1, ks = r & 1;
        int nn = ct * 16 + m;
#pragma unroll
        for (int j = 0; j < 8; j++) {
            int k = ks * 32 + q * 8 + j;
            o[j] = (k < HID && nn < HID2) ? f2bf(w1[((size_t)l * HID + k) * HID2 + nn]) : 0;
        }
        dstp = w1f + ((size_t)(l * 14 + ct * 2 + ks) * 64 + lane) * 8;
    } else if (gid < 90) {
        int g2 = gid - 42, l = g2 / 16, r = g2 % 16, ct = r >> 2, ks = r & 3;
        int nn = ct * 16 + m;
#pragma unroll
        for (int j = 0; j < 8; j++) {
            int k = ks * 32 + q * 8 + j;
            o[j] = (k < HID2 && nn < HID) ? f2bf(w2[((size_t)l * HID2 + k) * HID + nn]) : 0;
        }
        dstp = w2f + ((size_t)(l * 16 + ct * 4 + ks) * 64 + lane) * 8;
    } else {
        int g2 = gid - 90, ct = g2 >> 3, ks = g2 & 7;
        int nn = ct * 16 + m;
#pragma unroll
        for (int j = 0; j < 8; j++) {
            int kg = ks * 32 + q * 8 + j;
            int seg = kg >> 6, kk = kg & 63;
            o[j] = (kk < HID && nn < HID) ? f2bf(lin_w[((size_t)seg * HID + kk) * HID + nn]) : 0;
        }
        dstp = linf + ((size_t)(ct * 8 + ks) * 64 + lane) * 8;
    }
    uint4 u;
    u.x = (uint_t)o[0] | ((uint_t)o[1] << 16);
    u.y = (uint_t)o[2] | ((uint_t)o[3] << 16);
    u.z = (uint_t)o[4] | ((uint_t)o[5] << 16);
    u.w = (uint_t)o[6] | ((uint_t)o[7] << 16);
    *(uint4*)dstp = u;
}

// ---------- aggregation, L2-SLICED QUARTERS ----------
// r14 lesson: agg perf = many cheap waves (mega-kernel VGPR 168 -> 1 TB/s).
// r15: the 3.5 TB/s wall is L3->L2 refill of the 12.8MB table. Split channels
// into 4 quarters (32B/row -> 3.2MB slice FITS a 4MB XCD L2). q = blockIdx&3
// pins quarter q to XCDs {q, q+4} under the round-robin blockIdx%8 mapping ->
// per-XCD gather working set becomes L2-resident. Wave = 1 node-quarter:
// 2 lanes/edge (16B each), 32 edges/iter, butterfly reduce over lane bits 1..5.
// zbq is QUARTER-MAJOR so a block's 4 nodes x 32B = one contiguous 128B line
// (r4 write-combining lesson). Math per channel is bit-identical.
__global__ __launch_bounds__(256) void agg4_kernel(const ushort_t* __restrict__ hb,
                                                   const int* __restrict__ nrs,
                                                   const int* __restrict__ ndeg,
                                                   const int* __restrict__ srcsorted,
                                                   const float* __restrict__ eps,
                                                   ushort_t* __restrict__ zbq,
                                                   int n, int slstride) {
    int q = blockIdx.x & 3;
    int nodeg = blockIdx.x >> 2;
    int tid = threadIdx.x;
    int w = tid >> 6, lane = tid & 63;
    int node = nodeg * 4 + w;
    bool valid = (node < n);
    int nd = valid ? node : (n - 1);
    int e = lane >> 1, s = lane & 1;
    int beg = nrs[nd];
    int total = valid ? ndeg[nd] : 0;        // multiple of 16
    const char* hc = (const char*)hb;        // uniform base (SGPR)
    const char* sp = (const char*)srcsorted; // uniform base (SGPR)
    unsigned lq = (unsigned)(q * 32 + s * 16);   // byte offset of lane's 16B piece

    // AE*=(even ch exact) AO*=(odd ch noisy-hi) for the lane's 8 channels
    f32x2 AO0 = {0,0}, AO1 = {0,0}, AE0 = {0,0}, AE1 = {0,0};
    if (total > 0) {
        unsigned bo = (unsigned)(beg + e) * 4u;
        int f = *(const int*)(sp + bo);
        for (int b = 0; b < total; b += 32) {
            bool ok = (e < 16) | ((b + 16) < total);
            int e0 = ok ? f : n;             // masked slots -> zero row N
            f = *(const int*)(sp + bo + 128);    // prefetch next 32-group
            bo += 128;
            uint4 v = *(const uint4*)(hc + (((unsigned)e0 << 7) + lq));
            pkacc(AO0, rawpair(v.x, v.y)); pkacc(AO1, rawpair(v.z, v.w));
            pkacc(AE0, shlpair(v.x, v.y)); pkacc(AE1, shlpair(v.z, v.w));
        }
    }
    // reduce across 32 edge slots: xor lane bits 1..4 in-half, then cross-half
    pkacc(AO0, swz2<0x081F>(AO0)); pkacc(AO1, swz2<0x081F>(AO1));
    pkacc(AE0, swz2<0x081F>(AE0)); pkacc(AE1, swz2<0x081F>(AE1));
    pkacc(AO0, swz2<0x101F>(AO0)); pkacc(AO1, swz2<0x101F>(AO1));
    pkacc(AE0, swz2<0x101F>(AE0)); pkacc(AE1, swz2<0x101F>(AE1));
    pkacc(AO0, swz2<0x201F>(AO0)); pkacc(AO1, swz2<0x201F>(AO1));
    pkacc(AE0, swz2<0x201F>(AE0)); pkacc(AE1, swz2<0x201F>(AE1));
    pkacc(AO0, swz2<0x401F>(AO0)); pkacc(AO1, swz2<0x401F>(AO1));
    pkacc(AE0, swz2<0x401F>(AE0)); pkacc(AE1, swz2<0x401F>(AE1));
    pkacc(AO0, sh32(AO0)); pkacc(AO1, sh32(AO1));
    pkacc(AE0, sh32(AE0)); pkacc(AE1, sh32(AE1));
    if (lane < 2 && valid) {
        // lane 0: s=0 half, lane 1: s=1 half of this quarter
        // channel map: AE0=(c0,c2) AO0=(c1,c3) AE1=(c4,c6) AO1=(c5,c7)
        float sc = 1.0f + eps[0];
        uint4 sv = *(const uint4*)(hb + (size_t)node * 64 + q * 16 + s * 8);
        float o0 = fmaf(sc, bflo(sv.x), AE0.x), o1 = fmaf(sc, bfhi(sv.x), AO0.x);
        float o2 = fmaf(sc, bflo(sv.y), AE0.y), o3 = fmaf(sc, bfhi(sv.y), AO0.y);
        float o4 = fmaf(sc, bflo(sv.z), AE1.x), o5 = fmaf(sc, bfhi(sv.z), AO1.x);
        float o6 = fmaf(sc, bflo(sv.w), AE1.y), o7 = fmaf(sc, bfhi(sv.w), AO1.y);
        uint4 u;
        u.x = (uint_t)f2bf(o0) | ((uint_t)f2bf(o1) << 16);
        u.y = (uint_t)f2bf(o2) | ((uint_t)f2bf(o3) << 16);
        u.z = (uint_t)f2bf(o4) | ((uint_t)f2bf(o5) << 16);
        u.w = (uint_t)f2bf(o6) | ((uint_t)f2bf(o7) << 16);
        *(uint4*)(zbq + (size_t)q * slstride + (size_t)node * 16 + s * 8) = u;
    }
}

// ---------- MFMA fused 2-layer MLP (r12 body; A-frags from quarter-major zbq) ----------
template<int LAST>
__global__ __launch_bounds__(256) void mlp_kernel(const ushort_t* __restrict__ zbq,
                                                  const ushort_t* __restrict__ w1f,
                                                  const float* __restrict__ b1,
                                                  const ushort_t* __restrict__ w2f,
                                                  const float* __restrict__ b2,
                                                  ushort_t* __restrict__ hbout,
                                                  const ushort_t* __restrict__ xb,
                                                  const ushort_t* __restrict__ h1b,
                                                  const ushort_t* __restrict__ h2b,
                                                  const ushort_t* __restrict__ linf,
                                                  const float* __restrict__ lin_b,
                                                  float* __restrict__ out, int n, int slstride) {
    __shared__ ushort_t hid[64 * HSTRIDE];
    __shared__ ushort_t h3t[LAST ? 64 * 68 : 1];
    int tid = threadIdx.x;
    int w = tid >> 6, lane = tid & 63, m = lane & 15, q = lane >> 4;
    int nb = blockIdx.x * 64 + w * 16;
    int anode = min(nb + m, n - 1);
    // A-frag lane piece: channels [ks*32 + q*8, +8) = quarter ks*2+(q>>1), half q&1
    bf16x8 afr[2];
#pragma unroll
    for (int ks = 0; ks < 2; ks++) {
        int qq = ks * 2 + (q >> 1), ss = q & 1;
        afr[ks] = *(const bf16x8*)(zbq + (size_t)qq * slstride + (size_t)anode * 16 + ss * 8);
    }
    // pad-zero cols 104..135 of all 64 rows: one uint4 per thread
    *(uint4*)((char*)hid + (size_t)(tid >> 2) * 272 + 208 + (size_t)(tid & 3) * 16)
        = make_uint4(0, 0, 0, 0);
    __syncthreads();

    f32x4 acc1[7];
#pragma unroll
    for (int ct = 0; ct < 7; ct++) {
        int col = ct * 16 + m;
        float bv = (col < HID2) ? b1[col] : 0.f;
        acc1[ct] = (f32x4){bv, bv, bv, bv};
    }
#pragma unroll
    for (int ks = 0; ks < 2; ks++) {
#pragma unroll
        for (int ct = 0; ct < 7; ct++) {
            bf16x8 b = *(const bf16x8*)(w1f + ((size_t)(ct * 2 + ks) * 64 + lane) * 8);
            acc1[ct] = __builtin_amdgcn_mfma_f32_16x16x32_bf16(afr[ks], b, acc1[ct], 0, 0, 0);
        }
    }
#pragma unroll
    for (int ct = 0; ct < 7; ct++) {
#pragma unroll
        for (int r = 0; r < 4; r++) {
            float v = fmaxf(acc1[ct][r], 0.f);
            int row = w * 16 + q * 4 + r;
            hid[row * HSTRIDE + ct * 16 + m] = f2bf(v);
        }
    }
    f32x4 acc2[4];
#pragma unroll
    for (int ct = 0; ct < 4; ct++) {
        int col = ct * 16 + m;
        float bv = (col < HID) ? b2[col] : 0.f;
        acc2[ct] = (f32x4){bv, bv, bv, bv};
    }
#pragma unroll
    for (int ks = 0; ks < 4; ks++) {
        bf16x8 a = *(const bf16x8*)&hid[(w * 16 + m) * HSTRIDE + ks * 32 + q * 8];
#pragma unroll
        for (int ct = 0; ct < 4; ct++) {
            bf16x8 b = *(const bf16x8*)(w2f + ((size_t)(ct * 4 + ks) * 64 + lane) * 8);
            acc2[ct] = __builtin_amdgcn_mfma_f32_16x16x32_bf16(a, b, acc2[ct], 0, 0, 0);
        }
    }

    if (!LAST) {
        // stage acc2 -> hid (wave-private rows; same-wave DS in-order)
#pragma unroll
        for (int ct = 0; ct < 4; ct++) {
#pragma unroll
            for (int r = 0; r < 4; r++) {
                float v = fmaxf(acc2[ct][r], 0.f);
                hid[(w * 16 + q * 4 + r) * HSTRIDE + ct * 16 + m] = f2bf(v);
            }
        }
        // vectorized write-out: 2 x uint4 per lane covers 16 rows x 128B
#pragma unroll
        for (int k = 0; k < 2; k++) {
            int c = lane + k * 64;           // 0..127
            int row = c >> 3, seg = c & 7;
            int node = nb + row;
            if (node < n) {
                uint4 v = *(const uint4*)&hid[(w * 16 + row) * HSTRIDE + seg * 8];
                *(uint4*)(hbout + (size_t)node * 64 + seg * 8) = v;
            }
        }
    } else {
        // h3 (C-layout) -> LDS tile; wave-private rows, no barrier needed
#pragma unroll
        for (int ct = 0; ct < 4; ct++) {
#pragma unroll
            for (int r = 0; r < 4; r++) {
                float v = fmaxf(acc2[ct][r], 0.f);
                h3t[(w * 16 + q * 4 + r) * 68 + ct * 16 + m] = f2bf(v);
            }
        }
        // final: [16 x 256] @ [256 x 64]; segs x,h1,h2 from global, h3 from LDS
        f32x4 accF[4];
#pragma unroll
        for (int ct = 0; ct < 4; ct++) {
            int col = ct * 16 + m;
            float bv = (col < HID) ? lin_b[col] : 0.f;
            accF[ct] = (f32x4){bv, bv, bv, bv};
        }
        const ushort_t* segs[3] = {xb, h1b, h2b};
#pragma unroll
        for (int ks = 0; ks < 8; ks++) {
            bf16x8 a;
            if (ks < 6) {
                const ushort_t* p = segs[ks >> 1];
                a = *(const bf16x8*)(p + (size_t)anode * 64 + (ks & 1) * 32 + q * 8);
            } else {
                a = *(const bf16x8*)&h3t[(w * 16 + m) * 68 + (ks & 1) * 32 + q * 8];
            }
#pragma unroll
            for (int ct = 0; ct < 4; ct++) {
                bf16x8 b = *(const bf16x8*)(linf + ((size_t)(ct * 8 + ks) * 64 + lane) * 8);
                accF[ct] = __builtin_amdgcn_mfma_f32_16x16x32_bf16(a, b, accF[ct], 0, 0, 0);
            }
        }
#pragma unroll
        for (int ct = 0; ct < 4; ct++) {
            int col = ct * 16 + m;
            if (col < HID) {
#pragma unroll
                for (int r = 0; r < 4; r++) {
                    int node = nb + q * 4 + r;
                    if (node < n)
                        out[(size_t)node * HID + col] = accF[ct][r];
                }
            }
        }
    }
}

extern "C" void kernel_launch(void* const* d_in, const int* in_sizes, int n_in,
                              void* d_out, int out_size, void* d_ws, size_t ws_size,
                              hipStream_t stream) {
    const float* x     = (const float*)d_in[0];
    const int*   ei    = (const int*)d_in[1];
    const float* w1    = (const float*)d_in[2];
    const float* b1    = (const float*)d_in[3];
    const float* w2    = (const float*)d_in[4];
    const float* b2    = (const float*)d_in[5];
    const float* eps   = (const float*)d_in[6];
    const float* lin_w = (const float*)d_in[7];
    const float* lin_b = (const float*)d_in[8];
    float* out = (float*)d_out;

    const int N = in_sizes[0] / HID;       // 100000
    const int E = in_sizes[1] / 2;         // 3200000
    const int* src = ei;
    const int* dst = ei + E;

    const int NBIN = (N + 255) / 256;      // 391

    // ---- workspace layout; packed[] aliases the zbq(+h1b head) region:
    // pass1/mid fully consume packed before any agg writes zbq; h1b rows are
    // written only by mlp1 (after mid); h1b pad row N is beyond packed's span. ----
    char* p = (char*)d_ws;
    const size_t ROWS = (size_t)(N + 1) * 64 * 2;
    ushort_t* xb  = (ushort_t*)p;  p += ROWS;
    ushort_t* zbq = (ushort_t*)p;  p += ROWS;   // quarter-major: 4 x (NB4*4)*16 ushorts
    ushort_t* h1b = (ushort_t*)p;  p += ROWS;
    ushort_t* h2b = (ushort_t*)p;  p += ROWS;
    ushort_t* w1f = (ushort_t*)p;  p += 3 * 14 * 512 * 2;
    ushort_t* w2f = (ushort_t*)p;  p += 3 * 16 * 512 * 2;
    ushort_t* linf= (ushort_t*)p;  p += 32 * 512 * 2;
    int* gcnt     = (int*)p;       p += 512 * 4;
    int* nrs      = (int*)p;       p += (size_t)(N + 4) * 4;
    int* ndeg     = (int*)p;       p += (size_t)(N + 4) * 4;
    int* srcsorted = (int*)p;      p += (size_t)NBIN * SR_STRIDE * 4 + 256;  // + prefetch slack
    uint_t* packed = (uint_t*)zbq; // alias (see note above)

    ushort_t* hbs[3] = {xb, h1b, h2b};

    const int BLK = 256;
    const int NP1 = (E + P1_CHUNK - 1) / P1_CHUNK;   // 391
    const int NCONV = (N * 8 + BLK - 1) / BLK;       // 3125 (8 ch/thread)
    const int NBUCK = (N + 63) / 64;                 // 1563
    const int NB4 = (N + 3) / 4;                     // agg4 node-groups
    const int SLSTRIDE = NB4 * 4 * 16;               // ushorts per quarter slice
    dim3 blk(BLK);
    dim3 blk512(512);
    dim3 grid_agg4((size_t)NB4 * 4);

    // ---- front: memset + p1 + mid (r12-proven) ----
    hipMemsetAsync(gcnt, 0, 512 * sizeof(int), stream);
    pass1_kernel<<<NP1, blk512, 0, stream>>>(src, dst, gcnt, packed, E);
    mid_kernel<<<NBIN + NCONV + 1 + 31, blk, 0, stream>>>(packed, gcnt, srcsorted, nrs, ndeg,
                                                          x, w1, w2, lin_w,
                                                          xb, h1b, h2b,
                                                          w1f, w2f, linf,
                                                          N, NBIN, NCONV);

    // ---- layers 1,2 ----
    for (int l = 0; l < 2; l++) {
        agg4_kernel<<<grid_agg4, blk, 0, stream>>>(hbs[l], nrs, ndeg, srcsorted, eps + l,
                                                   zbq, N, SLSTRIDE);
        mlp_kernel<0><<<NBUCK, blk, 0, stream>>>(zbq,
                                                 w1f + (size_t)l * 14 * 512,
                                                 b1 + (size_t)l * HID2,
                                                 w2f + (size_t)l * 16 * 512,
                                                 b2 + (size_t)l * HID,
                                                 hbs[l + 1],
                                                 nullptr, nullptr, nullptr,
                                                 nullptr, nullptr, nullptr, N, SLSTRIDE);
    }
    // ---- layer 3 + fused final ----
    agg4_kernel<<<grid_agg4, blk, 0, stream>>>(h2b, nrs, ndeg, srcsorted, eps + 2,
                                               zbq, N, SLSTRIDE);
    mlp_kernel<1><<<NBUCK, blk, 0, stream>>>(zbq,
                                             w1f + 2 * 14 * 512,
                                             b1 + 2 * HID2,
                                             w2f + 2 * 16 * 512,
                                             b2 + 2 * HID,
                                             nullptr,
                                             xb, h1b, h2b,
                                             linf, lin_b, out, N, SLSTRIDE);
}